// Round 1
// baseline (2788.472 us; speedup 1.0000x reference)
//
#include <hip/hip_runtime.h>

// ---------------- problem constants ----------------
#define N_FRAMES 2048          // T*B
#define T_STEPS  128
#define BATCH    16
#define UNITS    128
#define NORM_SCALE 11.313708498984760390f  // sqrt(128)

// ---------------- workspace layout (float elements) ----------------
static const size_t OFF_W1P   = 0;            // 6144   : conv1 w [ky][kx][ic][oc] * (1/255)
static const size_t OFF_W2P   = 6144;         // 32768  : conv2 w [kk][ic][oc]
static const size_t OFF_W3P   = 38912;        // 36864  : conv3 w [kk][ic][oc]
static const size_t OFF_FCWP  = 75776;        // 1605632: fc w permuted to k'=p*64+c
static const size_t OFF_HSR   = 1681408;      // 262144
static const size_t OFF_HSI   = 1943552;      // 262144
static const size_t OFF_PROJR = 2205696;      // 262144
static const size_t OFF_PROJI = 2467840;      // 262144
static const size_t OFF_H     = 2729984;      // 1048576 : fc output [2048][512]
static const size_t OFF_Y2    = 3778560;      // 10616832: [2048][9][9][64]
static const size_t OFF_Y1    = 14395392;     // 26214400: [2048][20][20][32]
static const size_t OFF_Y3    = OFF_Y1;       // 6422528 : [2048][7][7][64] (reuses y1 after conv2)
// total = 40,609,792 floats = ~155 MiB

// ---------------- weight permutes ----------------
__global__ void permute_w1(const float* __restrict__ w, float* __restrict__ o) {
    int i = blockIdx.x * 256 + threadIdx.x;      // 6144
    if (i >= 32 * 3 * 64) return;
    int oc = i & 31; int r = i >> 5; int ic = r % 3; int kk = r / 3;
    int kx = kk & 7, ky = kk >> 3;
    o[i] = w[((oc * 3 + ic) * 8 + ky) * 8 + kx] * (1.0f / 255.0f);
}
__global__ void permute_w2(const float* __restrict__ w, float* __restrict__ o) {
    int i = blockIdx.x * 256 + threadIdx.x;      // 32768
    if (i >= 64 * 32 * 16) return;
    int oc = i & 63; int r = i >> 6; int ic = r & 31; int kk = r >> 5;
    int kx = kk & 3, ky = kk >> 2;
    o[i] = w[((oc * 32 + ic) * 4 + ky) * 4 + kx];
}
__global__ void permute_w3(const float* __restrict__ w, float* __restrict__ o) {
    int i = blockIdx.x * 256 + threadIdx.x;      // 36864
    if (i >= 64 * 64 * 9) return;
    int oc = i & 63; int r = i >> 6; int ic = r & 63; int kk = r >> 6;
    int kx = kk % 3, ky = kk / 3;
    o[i] = w[((oc * 64 + ic) * 3 + ky) * 3 + kx];
}
__global__ void permute_fcw(const float* __restrict__ w, float* __restrict__ o) {
    // o[(p*64+c)*512 + j] = w[(c*49+p)*512 + j]
    int i = blockIdx.x * 256 + threadIdx.x;      // 1605632
    if (i >= 3136 * 512) return;
    int j = i & 511; int kp = i >> 9; int c = kp & 63; int p = kp >> 6;
    o[i] = w[(size_t)(c * 49 + p) * 512 + j];
}

// ---------------- conv1: x[2048][84][84][3] -> y1[2048][20][20][32], 8x8 s4 ----------------
__global__ __launch_bounds__(256) void conv1_kernel(const float* __restrict__ x,
                                                    const float* __restrict__ w,
                                                    const float* __restrict__ b,
                                                    float* __restrict__ y) {
    int tid = threadIdx.x;
    int oc = tid & 31;
    int win = blockIdx.x * 8 + (tid >> 5);       // [0, 819200)
    int p = win % 400;
    int n = win / 400;
    int oy = p / 20, ox = p % 20;
    const float* xb = x + (size_t)n * 21168 + oy * 4 * 252 + ox * 12;
    float acc = 0.f;
#pragma unroll
    for (int ky = 0; ky < 8; ++ky) {
        const float4* xr4 = reinterpret_cast<const float4*>(xb + ky * 252);
        float vals[24];
#pragma unroll
        for (int q = 0; q < 6; ++q) {
            float4 v = xr4[q];
            vals[4 * q] = v.x; vals[4 * q + 1] = v.y; vals[4 * q + 2] = v.z; vals[4 * q + 3] = v.w;
        }
        const float* wr = w + ky * 24 * 32 + oc;
#pragma unroll
        for (int t = 0; t < 24; ++t) acc = fmaf(vals[t], wr[t * 32], acc);
    }
    y[(size_t)win * 32 + oc] = fmaxf(acc + b[oc], 0.f);
}

// ---------------- conv2: y1 -> y2[2048][9][9][64], 4x4 s2, 32ic ----------------
__global__ __launch_bounds__(256) void conv2_kernel(const float* __restrict__ y1,
                                                    const float* __restrict__ w,
                                                    const float* __restrict__ b,
                                                    float* __restrict__ y2) {
    int tid = threadIdx.x;
    int oc = tid & 63;
    int gid = blockIdx.x * 4 + (tid >> 6);       // (2048/8)*81 = 20736
    int p = gid % 81;
    int n0 = (gid / 81) * 8;
    int oy = p / 9, ox = p % 9;
    float acc[8] = {0, 0, 0, 0, 0, 0, 0, 0};
    const float* xb = y1 + (size_t)n0 * 12800 + oy * 2 * 640 + ox * 2 * 32;
#pragma unroll 1
    for (int kk = 0; kk < 16; ++kk) {
        int ky = kk >> 2, kx = kk & 3;
        const float* xk = xb + ky * 640 + kx * 32;
        const float* wk = w + kk * 2048 + oc;
#pragma unroll
        for (int icv = 0; icv < 8; ++icv) {
            float4 xv[8];
#pragma unroll
            for (int g = 0; g < 8; ++g)
                xv[g] = *reinterpret_cast<const float4*>(xk + (size_t)g * 12800 + icv * 4);
#pragma unroll
            for (int i4 = 0; i4 < 4; ++i4) {
                float wv = wk[(icv * 4 + i4) * 64];
#pragma unroll
                for (int g = 0; g < 8; ++g) {
                    float xs = (i4 == 0) ? xv[g].x : (i4 == 1) ? xv[g].y : (i4 == 2) ? xv[g].z : xv[g].w;
                    acc[g] = fmaf(xs, wv, acc[g]);
                }
            }
        }
    }
#pragma unroll
    for (int g = 0; g < 8; ++g)
        y2[((size_t)(n0 + g) * 81 + p) * 64 + oc] = fmaxf(acc[g] + b[oc], 0.f);
}

// ---------------- conv3: y2 -> y3[2048][7*7*64] (k' = p*64+c), 3x3 s1, 64ic ----------------
__global__ __launch_bounds__(256) void conv3_kernel(const float* __restrict__ y2,
                                                    const float* __restrict__ w,
                                                    const float* __restrict__ b,
                                                    float* __restrict__ y3) {
    int tid = threadIdx.x;
    int oc = tid & 63;
    int gid = blockIdx.x * 4 + (tid >> 6);       // (2048/8)*49 = 12544
    int p = gid % 49;
    int n0 = (gid / 49) * 8;
    int oy = p / 7, ox = p % 7;
    float acc[8] = {0, 0, 0, 0, 0, 0, 0, 0};
    const float* xb = y2 + (size_t)n0 * 5184 + oy * 576 + ox * 64;
#pragma unroll 1
    for (int kk = 0; kk < 9; ++kk) {
        int ky = kk / 3, kx = kk % 3;
        const float* xk = xb + ky * 576 + kx * 64;
        const float* wk = w + kk * 4096 + oc;
#pragma unroll 4
        for (int icv = 0; icv < 16; ++icv) {
            float4 xv[8];
#pragma unroll
            for (int g = 0; g < 8; ++g)
                xv[g] = *reinterpret_cast<const float4*>(xk + (size_t)g * 5184 + icv * 4);
#pragma unroll
            for (int i4 = 0; i4 < 4; ++i4) {
                float wv = wk[(icv * 4 + i4) * 64];
#pragma unroll
                for (int g = 0; g < 8; ++g) {
                    float xs = (i4 == 0) ? xv[g].x : (i4 == 1) ? xv[g].y : (i4 == 2) ? xv[g].z : xv[g].w;
                    acc[g] = fmaf(xs, wv, acc[g]);
                }
            }
        }
    }
#pragma unroll
    for (int g = 0; g < 8; ++g)
        y3[(size_t)(n0 + g) * 3136 + p * 64 + oc] = fmaxf(acc[g] + b[oc], 0.f);
}

// ---------------- FC: h[2048][512] = relu(y3 @ fcwp + fc_b) ----------------
__global__ __launch_bounds__(256) void fc_kernel(const float* __restrict__ A,
                                                 const float* __restrict__ B,
                                                 const float* __restrict__ bias,
                                                 float* __restrict__ C) {
    __shared__ float As[16][64];
    __shared__ float Bs[16][64];
    int tid = threadIdx.x;
    int bm = blockIdx.x & 31;       // 32 M-tiles
    int bn = blockIdx.x >> 5;       // 8 N-tiles
    int row0 = bm * 64, col0 = bn * 64;
    int tr = tid >> 4, tc = tid & 15;
    float acc[4][4] = {};
    int am = tid >> 2, ak = (tid & 3) * 4;
    int bk = tid >> 4, bn4 = (tid & 15) * 4;
    for (int k0 = 0; k0 < 3136; k0 += 16) {
        float4 av = *reinterpret_cast<const float4*>(A + (size_t)(row0 + am) * 3136 + k0 + ak);
        As[ak][am] = av.x; As[ak + 1][am] = av.y; As[ak + 2][am] = av.z; As[ak + 3][am] = av.w;
        float4 bv = *reinterpret_cast<const float4*>(B + (size_t)(k0 + bk) * 512 + col0 + bn4);
        *reinterpret_cast<float4*>(&Bs[bk][bn4]) = bv;
        __syncthreads();
#pragma unroll
        for (int kk = 0; kk < 16; ++kk) {
            float4 a4 = *reinterpret_cast<const float4*>(&As[kk][tr * 4]);
            float4 b4 = *reinterpret_cast<const float4*>(&Bs[kk][tc * 4]);
            const float a[4] = {a4.x, a4.y, a4.z, a4.w};
            const float bb[4] = {b4.x, b4.y, b4.z, b4.w};
#pragma unroll
            for (int i = 0; i < 4; ++i)
#pragma unroll
                for (int j = 0; j < 4; ++j) acc[i][j] = fmaf(a[i], bb[j], acc[i][j]);
        }
        __syncthreads();
    }
#pragma unroll
    for (int i = 0; i < 4; ++i)
#pragma unroll
        for (int j = 0; j < 4; ++j) {
            int r = row0 + tr * 4 + i, c = col0 + tc * 4 + j;
            C[(size_t)r * 512 + c] = fmaxf(acc[i][j] + bias[c], 0.f);
        }
}

// ---------------- proj: h[2048][512] @ win -> proj_{r,i}[2048][128] ----------------
__global__ __launch_bounds__(256) void proj_kernel(const float* __restrict__ h,
                                                   const float* __restrict__ winr,
                                                   const float* __restrict__ wini,
                                                   float* __restrict__ pr,
                                                   float* __restrict__ pi) {
    int idx = blockIdx.x * 256 + threadIdx.x;    // (2048/8)*128 = 32768
    int u = idx & 127;
    int n0 = (idx >> 7) * 8;
    float ar[8] = {}, ai[8] = {};
    for (int k = 0; k < 512; ++k) {
        float wrv = winr[k * 128 + u], wiv = wini[k * 128 + u];
#pragma unroll
        for (int g = 0; g < 8; ++g) {
            float hv = h[(size_t)(n0 + g) * 512 + k];
            ar[g] = fmaf(hv, wrv, ar[g]);
            ai[g] = fmaf(hv, wiv, ai[g]);
        }
    }
#pragma unroll
    for (int g = 0; g < 8; ++g) {
        pr[(size_t)(n0 + g) * 128 + u] = ar[g];
        pi[(size_t)(n0 + g) * 128 + u] = ai[g];
    }
}

// ---------------- RNN scan: one block per batch lane, sequential over T ----------------
__global__ __launch_bounds__(512) void scan_kernel(const float* __restrict__ done,
                                                   const float* __restrict__ sr0,
                                                   const float* __restrict__ si0,
                                                   const float* __restrict__ wrecr,
                                                   const float* __restrict__ wreci,
                                                   const float* __restrict__ pr,
                                                   const float* __restrict__ pi,
                                                   float* __restrict__ hsr,
                                                   float* __restrict__ hsi) {
    int b = blockIdx.x;
    int tid = threadIdx.x;
    int u = tid & 127;
    int s = tid >> 7;                     // k-split 0..3
    float wr[32], wi[32];
#pragma unroll
    for (int j = 0; j < 32; ++j) {
        int k = s * 32 + j;
        wr[j] = wrecr[k * 128 + u];
        wi[j] = wreci[k * 128 + u];
    }
    __shared__ float stR[128], stI[128];
    __shared__ float parR[4][128], parI[4][128];
    __shared__ float red[128];
    __shared__ float normsh;
    if (s == 0) { stR[u] = sr0[b * 128 + u]; stI[u] = si0[b * 128 + u]; }
    __syncthreads();
    for (int t = 0; t < T_STEPS; ++t) {
        float d = done[t * BATCH + b];
        if (s == 0) {
            float r = 1.f - d;
            stR[u] = r * stR[u] + d;      // blend toward init (1 + 0i)
            stI[u] = r * stI[u];
        }
        __syncthreads();
        float ar = 0.f, ai = 0.f;
#pragma unroll
        for (int j = 0; j < 32; ++j) {
            int k = s * 32 + j;
            float srk = stR[k], sik = stI[k];
            ar = fmaf(srk, wr[j], ar); ar = fmaf(-sik, wi[j], ar);
            ai = fmaf(srk, wi[j], ai); ai = fmaf(sik, wr[j], ai);
        }
        parR[s][u] = ar; parI[s][u] = ai;
        __syncthreads();
        float pre_r = 0.f, pre_i = 0.f;
        if (s == 0) {
            int np = (t * BATCH + b) * 128 + u;
            pre_r = parR[0][u] + parR[1][u] + parR[2][u] + parR[3][u] + pr[np];
            pre_i = parI[0][u] + parI[1][u] + parI[2][u] + parI[3][u] + pi[np];
            red[u] = pre_r * pre_r + pre_i * pre_i;
        }
        __syncthreads();
        if (tid < 64) {
            float v = red[tid] + red[tid + 64];
#pragma unroll
            for (int off = 32; off; off >>= 1) v += __shfl_down(v, off);
            if (tid == 0) normsh = v;
        }
        __syncthreads();
        if (s == 0) {
            float scale = NORM_SCALE / sqrtf(normsh);
            float nr = pre_r * scale, ni = pre_i * scale;
            stR[u] = nr; stI[u] = ni;
            int np = (t * BATCH + b) * 128 + u;
            hsr[np] = nr; hsi[np] = ni;
        }
        __syncthreads();
    }
}

// ---------------- heads: out[2048][7] ----------------
__global__ void heads_kernel(const float* __restrict__ hsr, const float* __restrict__ hsi,
                             const float* __restrict__ aw, const float* __restrict__ ab,
                             const float* __restrict__ cw, const float* __restrict__ cb,
                             float* __restrict__ out) {
    int idx = blockIdx.x * 256 + threadIdx.x;    // 14336
    if (idx >= N_FRAMES * 7) return;
    int j = idx % 7;
    int n = idx / 7;
    float acc;
    if (j < 6) {
        acc = ab[j];
        for (int k = 0; k < 128; ++k) acc = fmaf(hsr[n * 128 + k], aw[k * 6 + j], acc);
        for (int k = 0; k < 128; ++k) acc = fmaf(hsi[n * 128 + k], aw[(128 + k) * 6 + j], acc);
    } else {
        acc = cb[0];
        for (int k = 0; k < 128; ++k) acc = fmaf(hsr[n * 128 + k], cw[k], acc);
        for (int k = 0; k < 128; ++k) acc = fmaf(hsi[n * 128 + k], cw[128 + k], acc);
    }
    out[idx] = acc;
}

// ---------------- launch ----------------
extern "C" void kernel_launch(void* const* d_in, const int* in_sizes, int n_in,
                              void* d_out, int out_size, void* d_ws, size_t ws_size,
                              hipStream_t stream) {
    const float* x        = (const float*)d_in[0];
    const float* done     = (const float*)d_in[1];
    const float* sr0      = (const float*)d_in[2];
    const float* si0      = (const float*)d_in[3];
    const float* conv1_w  = (const float*)d_in[4];
    const float* conv1_b  = (const float*)d_in[5];
    const float* conv2_w  = (const float*)d_in[6];
    const float* conv2_b  = (const float*)d_in[7];
    const float* conv3_w  = (const float*)d_in[8];
    const float* conv3_b  = (const float*)d_in[9];
    const float* fc_w     = (const float*)d_in[10];
    const float* fc_b     = (const float*)d_in[11];
    const float* win_r    = (const float*)d_in[12];
    const float* win_i    = (const float*)d_in[13];
    const float* wrec_r   = (const float*)d_in[14];
    const float* wrec_i   = (const float*)d_in[15];
    const float* actor_w  = (const float*)d_in[16];
    const float* actor_b  = (const float*)d_in[17];
    const float* critic_w = (const float*)d_in[18];
    const float* critic_b = (const float*)d_in[19];

    float* ws = (float*)d_ws;
    float* w1p  = ws + OFF_W1P;
    float* w2p  = ws + OFF_W2P;
    float* w3p  = ws + OFF_W3P;
    float* fcwp = ws + OFF_FCWP;
    float* hsr  = ws + OFF_HSR;
    float* hsi  = ws + OFF_HSI;
    float* prj  = ws + OFF_PROJR;
    float* pij  = ws + OFF_PROJI;
    float* h    = ws + OFF_H;
    float* y2   = ws + OFF_Y2;
    float* y1   = ws + OFF_Y1;
    float* y3   = ws + OFF_Y3;
    float* outp = (float*)d_out;

    hipLaunchKernelGGL(permute_w1, dim3(24), dim3(256), 0, stream, conv1_w, w1p);
    hipLaunchKernelGGL(permute_w2, dim3(128), dim3(256), 0, stream, conv2_w, w2p);
    hipLaunchKernelGGL(permute_w3, dim3(144), dim3(256), 0, stream, conv3_w, w3p);
    hipLaunchKernelGGL(permute_fcw, dim3(6272), dim3(256), 0, stream, fc_w, fcwp);

    hipLaunchKernelGGL(conv1_kernel, dim3(102400), dim3(256), 0, stream, x, w1p, conv1_b, y1);
    hipLaunchKernelGGL(conv2_kernel, dim3(5184), dim3(256), 0, stream, y1, w2p, conv2_b, y2);
    hipLaunchKernelGGL(conv3_kernel, dim3(3136), dim3(256), 0, stream, y2, w3p, conv3_b, y3);
    hipLaunchKernelGGL(fc_kernel, dim3(256), dim3(256), 0, stream, y3, fcwp, fc_b, h);
    hipLaunchKernelGGL(proj_kernel, dim3(128), dim3(256), 0, stream, h, win_r, win_i, prj, pij);
    hipLaunchKernelGGL(scan_kernel, dim3(16), dim3(512), 0, stream,
                       done, sr0, si0, wrec_r, wrec_i, prj, pij, hsr, hsi);
    hipLaunchKernelGGL(heads_kernel, dim3(56), dim3(256), 0, stream,
                       hsr, hsi, actor_w, actor_b, critic_w, critic_b, outp);
}

// Round 2
// 1921.458 us; speedup vs baseline: 1.4512x; 1.4512x over previous
//
#include <hip/hip_runtime.h>

// ---------------- problem constants ----------------
#define N_FRAMES 2048          // T*B
#define T_STEPS  128
#define BATCH    16
#define UNITS    128
#define NORM_SCALE 11.313708498984760390f  // sqrt(128)

// ---------------- workspace layout (float elements) ----------------
static const size_t OFF_W1P   = 0;            // 6144   : conv1 w [ky][kx][ic][oc] * (1/255)
static const size_t OFF_W2P   = 6144;         // 32768  : conv2 w [kk][ic][oc]
static const size_t OFF_W3P   = 38912;        // 36864  : conv3 w [kk][ic][oc]
static const size_t OFF_FCWP  = 75776;        // 1605632: fc w permuted to k'=p*64+c
static const size_t OFF_HSR   = 1681408;      // 262144
static const size_t OFF_HSI   = 1943552;      // 262144
static const size_t OFF_PROJR = 2205696;      // 262144
static const size_t OFF_PROJI = 2467840;      // 262144
static const size_t OFF_H     = 2729984;      // 1048576 : fc output [2048][512]
static const size_t OFF_Y2    = 3778560;      // 10616832: [2048][9][9][64]
static const size_t OFF_Y1    = 14395392;     // 26214400: [2048][20][20][32]
static const size_t OFF_Y3    = OFF_Y1;       // 6422528 : [2048][7][7][64] (reuses y1 after conv2)

// ---------------- weight permutes ----------------
__global__ void permute_w1(const float* __restrict__ w, float* __restrict__ o) {
    int i = blockIdx.x * 256 + threadIdx.x;      // 6144
    if (i >= 32 * 3 * 64) return;
    int oc = i & 31; int r = i >> 5; int ic = r % 3; int kk = r / 3;
    int kx = kk & 7, ky = kk >> 3;
    o[i] = w[((oc * 3 + ic) * 8 + ky) * 8 + kx] * (1.0f / 255.0f);
}
__global__ void permute_w2(const float* __restrict__ w, float* __restrict__ o) {
    int i = blockIdx.x * 256 + threadIdx.x;      // 32768
    if (i >= 64 * 32 * 16) return;
    int oc = i & 63; int r = i >> 6; int ic = r & 31; int kk = r >> 5;
    int kx = kk & 3, ky = kk >> 2;
    o[i] = w[((oc * 32 + ic) * 4 + ky) * 4 + kx];
}
__global__ void permute_w3(const float* __restrict__ w, float* __restrict__ o) {
    int i = blockIdx.x * 256 + threadIdx.x;      // 36864
    if (i >= 64 * 64 * 9) return;
    int oc = i & 63; int r = i >> 6; int ic = r & 63; int kk = r >> 6;
    int kx = kk % 3, ky = kk / 3;
    o[i] = w[((oc * 64 + ic) * 3 + ky) * 3 + kx];
}
__global__ void permute_fcw(const float* __restrict__ w, float* __restrict__ o) {
    // o[(p*64+c)*512 + j] = w[(c*49+p)*512 + j]
    int i = blockIdx.x * 256 + threadIdx.x;      // 1605632
    if (i >= 3136 * 512) return;
    int j = i & 511; int kp = i >> 9; int c = kp & 63; int p = kp >> 6;
    o[i] = w[(size_t)(c * 49 + p) * 512 + j];
}

// ---------------- conv1 v2: LDS-staged, register-blocked ----------------
// block = (image n, half hb); 4096 blocks x 256 threads.
// LDS: 44 x-rows (44*252 floats) + weights [192][32]. ~69 KB -> 2 blocks/CU.
// thread: ocg = tid&7 (4 oc), pg = tid>>3 (8 pixels, p = j*25+pg), active pg<25.
__global__ __launch_bounds__(256) void conv1_kernel(const float* __restrict__ x,
                                                    const float* __restrict__ w,
                                                    const float* __restrict__ b,
                                                    float* __restrict__ y) {
    __shared__ float xs[44 * 252];    // 44352 B
    __shared__ float wsm[192 * 32];   // 24576 B
    int tid = threadIdx.x;
    int blk = blockIdx.x;
    int n = blk >> 1, hb = blk & 1;

    // stage x rows hb*40 .. hb*40+43 (float4, fully coalesced)
    const float4* xb4 = reinterpret_cast<const float4*>(x + (size_t)n * 21168 + hb * 40 * 252);
    float4* xs4 = reinterpret_cast<float4*>(xs);
    for (int i = tid; i < 2772; i += 256) xs4[i] = xb4[i];
    // stage weights
    const float4* w4 = reinterpret_cast<const float4*>(w);
    float4* ws4 = reinterpret_cast<float4*>(wsm);
    for (int i = tid; i < 1536; i += 256) ws4[i] = w4[i];
    __syncthreads();

    int ocg = tid & 7;
    int pg = tid >> 3;
    if (pg < 25) {
        // per-pixel base offsets (pixels p = j*25 + pg, local to this half)
        int baseo[8];
        int pidx[8];
#pragma unroll
        for (int j = 0; j < 8; ++j) {
            int p = j * 25 + pg;
            pidx[j] = p;
            int oy = p / 20, ox = p % 20;
            baseo[j] = oy * 1008 + ox * 12;   // (oy*4)*252 + ox*12
        }
        float acc[8][4] = {};
#pragma unroll 2
        for (int ky = 0; ky < 8; ++ky) {
#pragma unroll
            for (int rq = 0; rq < 6; ++rq) {
                // 4 weight quads: k = ky*24 + rq*4 + m
                float4 wv0 = *reinterpret_cast<const float4*>(&wsm[(ky * 24 + rq * 4 + 0) * 32 + ocg * 4]);
                float4 wv1 = *reinterpret_cast<const float4*>(&wsm[(ky * 24 + rq * 4 + 1) * 32 + ocg * 4]);
                float4 wv2 = *reinterpret_cast<const float4*>(&wsm[(ky * 24 + rq * 4 + 2) * 32 + ocg * 4]);
                float4 wv3 = *reinterpret_cast<const float4*>(&wsm[(ky * 24 + rq * 4 + 3) * 32 + ocg * 4]);
#pragma unroll
                for (int j = 0; j < 8; ++j) {
                    float4 xv = *reinterpret_cast<const float4*>(&xs[baseo[j] + ky * 252 + rq * 4]);
                    acc[j][0] = fmaf(xv.x, wv0.x, acc[j][0]);
                    acc[j][1] = fmaf(xv.x, wv0.y, acc[j][1]);
                    acc[j][2] = fmaf(xv.x, wv0.z, acc[j][2]);
                    acc[j][3] = fmaf(xv.x, wv0.w, acc[j][3]);
                    acc[j][0] = fmaf(xv.y, wv1.x, acc[j][0]);
                    acc[j][1] = fmaf(xv.y, wv1.y, acc[j][1]);
                    acc[j][2] = fmaf(xv.y, wv1.z, acc[j][2]);
                    acc[j][3] = fmaf(xv.y, wv1.w, acc[j][3]);
                    acc[j][0] = fmaf(xv.z, wv2.x, acc[j][0]);
                    acc[j][1] = fmaf(xv.z, wv2.y, acc[j][1]);
                    acc[j][2] = fmaf(xv.z, wv2.z, acc[j][2]);
                    acc[j][3] = fmaf(xv.z, wv2.w, acc[j][3]);
                    acc[j][0] = fmaf(xv.w, wv3.x, acc[j][0]);
                    acc[j][1] = fmaf(xv.w, wv3.y, acc[j][1]);
                    acc[j][2] = fmaf(xv.w, wv3.z, acc[j][2]);
                    acc[j][3] = fmaf(xv.w, wv3.w, acc[j][3]);
                }
            }
        }
        float4 bv = reinterpret_cast<const float4*>(b)[ocg];
        const float bb[4] = {bv.x, bv.y, bv.z, bv.w};
#pragma unroll
        for (int j = 0; j < 8; ++j) {
            float4 o;
            o.x = fmaxf(acc[j][0] + bb[0], 0.f);
            o.y = fmaxf(acc[j][1] + bb[1], 0.f);
            o.z = fmaxf(acc[j][2] + bb[2], 0.f);
            o.w = fmaxf(acc[j][3] + bb[3], 0.f);
            size_t off = ((size_t)(n * 400 + hb * 200 + pidx[j]) * 32) + ocg * 4;
            *reinterpret_cast<float4*>(&y[off]) = o;
        }
    }
}

// ---------------- conv2: y1 -> y2[2048][9][9][64], 4x4 s2, 32ic ----------------
__global__ __launch_bounds__(256) void conv2_kernel(const float* __restrict__ y1,
                                                    const float* __restrict__ w,
                                                    const float* __restrict__ b,
                                                    float* __restrict__ y2) {
    int tid = threadIdx.x;
    int oc = tid & 63;
    int gid = blockIdx.x * 4 + (tid >> 6);       // (2048/8)*81 = 20736
    int p = gid % 81;
    int n0 = (gid / 81) * 8;
    int oy = p / 9, ox = p % 9;
    float acc[8] = {0, 0, 0, 0, 0, 0, 0, 0};
    const float* xb = y1 + (size_t)n0 * 12800 + oy * 2 * 640 + ox * 2 * 32;
#pragma unroll 1
    for (int kk = 0; kk < 16; ++kk) {
        int ky = kk >> 2, kx = kk & 3;
        const float* xk = xb + ky * 640 + kx * 32;
        const float* wk = w + kk * 2048 + oc;
#pragma unroll
        for (int icv = 0; icv < 8; ++icv) {
            float4 xv[8];
#pragma unroll
            for (int g = 0; g < 8; ++g)
                xv[g] = *reinterpret_cast<const float4*>(xk + (size_t)g * 12800 + icv * 4);
#pragma unroll
            for (int i4 = 0; i4 < 4; ++i4) {
                float wv = wk[(icv * 4 + i4) * 64];
#pragma unroll
                for (int g = 0; g < 8; ++g) {
                    float xs = (i4 == 0) ? xv[g].x : (i4 == 1) ? xv[g].y : (i4 == 2) ? xv[g].z : xv[g].w;
                    acc[g] = fmaf(xs, wv, acc[g]);
                }
            }
        }
    }
#pragma unroll
    for (int g = 0; g < 8; ++g)
        y2[((size_t)(n0 + g) * 81 + p) * 64 + oc] = fmaxf(acc[g] + b[oc], 0.f);
}

// ---------------- conv3: y2 -> y3[2048][7*7*64] (k' = p*64+c), 3x3 s1, 64ic ----------------
__global__ __launch_bounds__(256) void conv3_kernel(const float* __restrict__ y2,
                                                    const float* __restrict__ w,
                                                    const float* __restrict__ b,
                                                    float* __restrict__ y3) {
    int tid = threadIdx.x;
    int oc = tid & 63;
    int gid = blockIdx.x * 4 + (tid >> 6);       // (2048/8)*49 = 12544
    int p = gid % 49;
    int n0 = (gid / 49) * 8;
    int oy = p / 7, ox = p % 7;
    float acc[8] = {0, 0, 0, 0, 0, 0, 0, 0};
    const float* xb = y2 + (size_t)n0 * 5184 + oy * 576 + ox * 64;
#pragma unroll 1
    for (int kk = 0; kk < 9; ++kk) {
        int ky = kk / 3, kx = kk % 3;
        const float* xk = xb + ky * 576 + kx * 64;
        const float* wk = w + kk * 4096 + oc;
#pragma unroll 4
        for (int icv = 0; icv < 16; ++icv) {
            float4 xv[8];
#pragma unroll
            for (int g = 0; g < 8; ++g)
                xv[g] = *reinterpret_cast<const float4*>(xk + (size_t)g * 5184 + icv * 4);
#pragma unroll
            for (int i4 = 0; i4 < 4; ++i4) {
                float wv = wk[(icv * 4 + i4) * 64];
#pragma unroll
                for (int g = 0; g < 8; ++g) {
                    float xs = (i4 == 0) ? xv[g].x : (i4 == 1) ? xv[g].y : (i4 == 2) ? xv[g].z : xv[g].w;
                    acc[g] = fmaf(xs, wv, acc[g]);
                }
            }
        }
    }
#pragma unroll
    for (int g = 0; g < 8; ++g)
        y3[(size_t)(n0 + g) * 3136 + p * 64 + oc] = fmaxf(acc[g] + b[oc], 0.f);
}

// ---------------- FC: h[2048][512] = relu(y3 @ fcwp + fc_b) ----------------
__global__ __launch_bounds__(256) void fc_kernel(const float* __restrict__ A,
                                                 const float* __restrict__ B,
                                                 const float* __restrict__ bias,
                                                 float* __restrict__ C) {
    __shared__ float As[16][64];
    __shared__ float Bs[16][64];
    int tid = threadIdx.x;
    int bm = blockIdx.x & 31;       // 32 M-tiles
    int bn = blockIdx.x >> 5;       // 8 N-tiles
    int row0 = bm * 64, col0 = bn * 64;
    int tr = tid >> 4, tc = tid & 15;
    float acc[4][4] = {};
    int am = tid >> 2, ak = (tid & 3) * 4;
    int bk = tid >> 4, bn4 = (tid & 15) * 4;
    for (int k0 = 0; k0 < 3136; k0 += 16) {
        float4 av = *reinterpret_cast<const float4*>(A + (size_t)(row0 + am) * 3136 + k0 + ak);
        As[ak][am] = av.x; As[ak + 1][am] = av.y; As[ak + 2][am] = av.z; As[ak + 3][am] = av.w;
        float4 bv = *reinterpret_cast<const float4*>(B + (size_t)(k0 + bk) * 512 + col0 + bn4);
        *reinterpret_cast<float4*>(&Bs[bk][bn4]) = bv;
        __syncthreads();
#pragma unroll
        for (int kk = 0; kk < 16; ++kk) {
            float4 a4 = *reinterpret_cast<const float4*>(&As[kk][tr * 4]);
            float4 b4 = *reinterpret_cast<const float4*>(&Bs[kk][tc * 4]);
            const float a[4] = {a4.x, a4.y, a4.z, a4.w};
            const float bb[4] = {b4.x, b4.y, b4.z, b4.w};
#pragma unroll
            for (int i = 0; i < 4; ++i)
#pragma unroll
                for (int j = 0; j < 4; ++j) acc[i][j] = fmaf(a[i], bb[j], acc[i][j]);
        }
        __syncthreads();
    }
#pragma unroll
    for (int i = 0; i < 4; ++i)
#pragma unroll
        for (int j = 0; j < 4; ++j) {
            int r = row0 + tr * 4 + i, c = col0 + tc * 4 + j;
            C[(size_t)r * 512 + c] = fmaxf(acc[i][j] + bias[c], 0.f);
        }
}

// ---------------- proj: h[2048][512] @ win -> proj_{r,i}[2048][128] ----------------
__global__ __launch_bounds__(256) void proj_kernel(const float* __restrict__ h,
                                                   const float* __restrict__ winr,
                                                   const float* __restrict__ wini,
                                                   float* __restrict__ pr,
                                                   float* __restrict__ pi) {
    int idx = blockIdx.x * 256 + threadIdx.x;    // (2048/8)*128 = 32768
    int u = idx & 127;
    int n0 = (idx >> 7) * 8;
    float ar[8] = {}, ai[8] = {};
    for (int k = 0; k < 512; ++k) {
        float wrv = winr[k * 128 + u], wiv = wini[k * 128 + u];
#pragma unroll
        for (int g = 0; g < 8; ++g) {
            float hv = h[(size_t)(n0 + g) * 512 + k];
            ar[g] = fmaf(hv, wrv, ar[g]);
            ai[g] = fmaf(hv, wiv, ai[g]);
        }
    }
#pragma unroll
    for (int g = 0; g < 8; ++g) {
        pr[(size_t)(n0 + g) * 128 + u] = ar[g];
        pi[(size_t)(n0 + g) * 128 + u] = ai[g];
    }
}

// ---------------- RNN scan: one block per batch lane, sequential over T ----------------
__global__ __launch_bounds__(512) void scan_kernel(const float* __restrict__ done,
                                                   const float* __restrict__ sr0,
                                                   const float* __restrict__ si0,
                                                   const float* __restrict__ wrecr,
                                                   const float* __restrict__ wreci,
                                                   const float* __restrict__ pr,
                                                   const float* __restrict__ pi,
                                                   float* __restrict__ hsr,
                                                   float* __restrict__ hsi) {
    int b = blockIdx.x;
    int tid = threadIdx.x;
    int u = tid & 127;
    int s = tid >> 7;                     // k-split 0..3
    float wr[32], wi[32];
#pragma unroll
    for (int j = 0; j < 32; ++j) {
        int k = s * 32 + j;
        wr[j] = wrecr[k * 128 + u];
        wi[j] = wreci[k * 128 + u];
    }
    __shared__ float stR[128], stI[128];
    __shared__ float parR[4][128], parI[4][128];
    __shared__ float red[128];
    __shared__ float normsh;
    if (s == 0) { stR[u] = sr0[b * 128 + u]; stI[u] = si0[b * 128 + u]; }
    __syncthreads();
    for (int t = 0; t < T_STEPS; ++t) {
        float d = done[t * BATCH + b];
        if (s == 0) {
            float r = 1.f - d;
            stR[u] = r * stR[u] + d;      // blend toward init (1 + 0i)
            stI[u] = r * stI[u];
        }
        __syncthreads();
        float ar = 0.f, ai = 0.f;
#pragma unroll
        for (int j = 0; j < 32; ++j) {
            int k = s * 32 + j;
            float srk = stR[k], sik = stI[k];
            ar = fmaf(srk, wr[j], ar); ar = fmaf(-sik, wi[j], ar);
            ai = fmaf(srk, wi[j], ai); ai = fmaf(sik, wr[j], ai);
        }
        parR[s][u] = ar; parI[s][u] = ai;
        __syncthreads();
        float pre_r = 0.f, pre_i = 0.f;
        if (s == 0) {
            int np = (t * BATCH + b) * 128 + u;
            pre_r = parR[0][u] + parR[1][u] + parR[2][u] + parR[3][u] + pr[np];
            pre_i = parI[0][u] + parI[1][u] + parI[2][u] + parI[3][u] + pi[np];
            red[u] = pre_r * pre_r + pre_i * pre_i;
        }
        __syncthreads();
        if (tid < 64) {
            float v = red[tid] + red[tid + 64];
#pragma unroll
            for (int off = 32; off; off >>= 1) v += __shfl_down(v, off);
            if (tid == 0) normsh = v;
        }
        __syncthreads();
        if (s == 0) {
            float scale = NORM_SCALE / sqrtf(normsh);
            float nr = pre_r * scale, ni = pre_i * scale;
            stR[u] = nr; stI[u] = ni;
            int np = (t * BATCH + b) * 128 + u;
            hsr[np] = nr; hsi[np] = ni;
        }
        __syncthreads();
    }
}

// ---------------- heads: out[2048][7] ----------------
__global__ void heads_kernel(const float* __restrict__ hsr, const float* __restrict__ hsi,
                             const float* __restrict__ aw, const float* __restrict__ ab,
                             const float* __restrict__ cw, const float* __restrict__ cb,
                             float* __restrict__ out) {
    int idx = blockIdx.x * 256 + threadIdx.x;    // 14336
    if (idx >= N_FRAMES * 7) return;
    int j = idx % 7;
    int n = idx / 7;
    float acc;
    if (j < 6) {
        acc = ab[j];
        for (int k = 0; k < 128; ++k) acc = fmaf(hsr[n * 128 + k], aw[k * 6 + j], acc);
        for (int k = 0; k < 128; ++k) acc = fmaf(hsi[n * 128 + k], aw[(128 + k) * 6 + j], acc);
    } else {
        acc = cb[0];
        for (int k = 0; k < 128; ++k) acc = fmaf(hsr[n * 128 + k], cw[k], acc);
        for (int k = 0; k < 128; ++k) acc = fmaf(hsi[n * 128 + k], cw[128 + k], acc);
    }
    out[idx] = acc;
}

// ---------------- launch ----------------
extern "C" void kernel_launch(void* const* d_in, const int* in_sizes, int n_in,
                              void* d_out, int out_size, void* d_ws, size_t ws_size,
                              hipStream_t stream) {
    const float* x        = (const float*)d_in[0];
    const float* done     = (const float*)d_in[1];
    const float* sr0      = (const float*)d_in[2];
    const float* si0      = (const float*)d_in[3];
    const float* conv1_w  = (const float*)d_in[4];
    const float* conv1_b  = (const float*)d_in[5];
    const float* conv2_w  = (const float*)d_in[6];
    const float* conv2_b  = (const float*)d_in[7];
    const float* conv3_w  = (const float*)d_in[8];
    const float* conv3_b  = (const float*)d_in[9];
    const float* fc_w     = (const float*)d_in[10];
    const float* fc_b     = (const float*)d_in[11];
    const float* win_r    = (const float*)d_in[12];
    const float* win_i    = (const float*)d_in[13];
    const float* wrec_r   = (const float*)d_in[14];
    const float* wrec_i   = (const float*)d_in[15];
    const float* actor_w  = (const float*)d_in[16];
    const float* actor_b  = (const float*)d_in[17];
    const float* critic_w = (const float*)d_in[18];
    const float* critic_b = (const float*)d_in[19];

    float* ws = (float*)d_ws;
    float* w1p  = ws + OFF_W1P;
    float* w2p  = ws + OFF_W2P;
    float* w3p  = ws + OFF_W3P;
    float* fcwp = ws + OFF_FCWP;
    float* hsr  = ws + OFF_HSR;
    float* hsi  = ws + OFF_HSI;
    float* prj  = ws + OFF_PROJR;
    float* pij  = ws + OFF_PROJI;
    float* h    = ws + OFF_H;
    float* y2   = ws + OFF_Y2;
    float* y1   = ws + OFF_Y1;
    float* y3   = ws + OFF_Y3;
    float* outp = (float*)d_out;

    hipLaunchKernelGGL(permute_w1, dim3(24), dim3(256), 0, stream, conv1_w, w1p);
    hipLaunchKernelGGL(permute_w2, dim3(128), dim3(256), 0, stream, conv2_w, w2p);
    hipLaunchKernelGGL(permute_w3, dim3(144), dim3(256), 0, stream, conv3_w, w3p);
    hipLaunchKernelGGL(permute_fcw, dim3(6272), dim3(256), 0, stream, fc_w, fcwp);

    hipLaunchKernelGGL(conv1_kernel, dim3(4096), dim3(256), 0, stream, x, w1p, conv1_b, y1);
    hipLaunchKernelGGL(conv2_kernel, dim3(5184), dim3(256), 0, stream, y1, w2p, conv2_b, y2);
    hipLaunchKernelGGL(conv3_kernel, dim3(3136), dim3(256), 0, stream, y2, w3p, conv3_b, y3);
    hipLaunchKernelGGL(fc_kernel, dim3(256), dim3(256), 0, stream, y3, fcwp, fc_b, h);
    hipLaunchKernelGGL(proj_kernel, dim3(128), dim3(256), 0, stream, h, win_r, win_i, prj, pij);
    hipLaunchKernelGGL(scan_kernel, dim3(16), dim3(512), 0, stream,
                       done, sr0, si0, wrec_r, wrec_i, prj, pij, hsr, hsi);
    hipLaunchKernelGGL(heads_kernel, dim3(56), dim3(256), 0, stream,
                       hsr, hsi, actor_w, actor_b, critic_w, critic_b, outp);
}